// Round 1
// baseline (320.867 us; speedup 1.0000x reference)
//
#include <hip/hip_runtime.h>
#include <stdint.h>
#include <math.h>

// Match XLA's default (non-contracted) f32 arithmetic: keeps floor()/compare
// boundaries (bilinear taps, erase box, gridmask) aligned with the reference.
#pragma clang fp contract(off)

// Modern JAX (>=0.4.30) defaults jax_threefry_partitionable=True.
// If this round fails with absmax ~1.0, flip to 0 (legacy iota-halves mode).
#define JAX_PARTITIONABLE 1

struct KeyPair { uint32_t hi, lo; };

struct AugKeys {
  KeyPair k1g, k2g, k3g, k4g;      // affine: angle, shear, scale, translate
  KeyPair kf;                      // hflip bernoulli
  KeyPair kbc, kcc, ksc;           // brightness, contrast, saturation
  KeyPair kb;                      // blur bernoulli
  KeyPair ka, kr, kt, kl, kv, kp;  // erasing: area, ratio, top, left, fill, apply
  KeyPair kd, kp2;                 // gridmask: d, apply
};

__host__ __device__ __forceinline__ uint32_t rotl32(uint32_t x, int r) {
  return (x << r) | (x >> (32 - r));
}

// JAX threefry2x32: 20 rounds, key injection every 4.
__host__ __device__ __forceinline__ void threefry2x32(uint32_t k0, uint32_t k1,
                                                      uint32_t x0, uint32_t x1,
                                                      uint32_t& o0, uint32_t& o1) {
  const uint32_t ks0 = k0, ks1 = k1, ks2 = k0 ^ k1 ^ 0x1BD11BDAu;
  x0 += ks0; x1 += ks1;
#define TF_R(r) { x0 += x1; x1 = rotl32(x1, (r)); x1 ^= x0; }
  TF_R(13) TF_R(15) TF_R(26) TF_R(6)
  x0 += ks1; x1 += ks2 + 1u;
  TF_R(17) TF_R(29) TF_R(16) TF_R(24)
  x0 += ks2; x1 += ks0 + 2u;
  TF_R(13) TF_R(15) TF_R(26) TF_R(6)
  x0 += ks0; x1 += ks1 + 3u;
  TF_R(17) TF_R(29) TF_R(16) TF_R(24)
  x0 += ks1; x1 += ks2 + 4u;
  TF_R(13) TF_R(15) TF_R(26) TF_R(6)
  x0 += ks2; x1 += ks0 + 5u;
#undef TF_R
  o0 = x0; o1 = x1;
}

// Element i of jax random_bits(key, 32, (n,)) (flat index).
__host__ __device__ __forceinline__ uint32_t jax_rbits32(KeyPair k, uint32_t i, uint32_t n) {
#if JAX_PARTITIONABLE
  (void)n;
  uint32_t a, b; threefry2x32(k.hi, k.lo, 0u, i, a, b);
  return a ^ b;  // 32-bit case folds both outputs
#else
  const uint32_t h = n >> 1;  // n even for all draws here
  uint32_t a, b;
  if (i < h) { threefry2x32(k.hi, k.lo, i, i + h, a, b); return a; }
  threefry2x32(k.hi, k.lo, i - h, i, a, b); return b;
#endif
}

// Child j of jax.random.split(k, n).
__host__ __device__ __forceinline__ KeyPair jax_split_child(KeyPair k, uint32_t j, uint32_t n) {
#if JAX_PARTITIONABLE
  (void)n;
  uint32_t a, b; threefry2x32(k.hi, k.lo, 0u, j, a, b);
  KeyPair r; r.hi = a; r.lo = b; return r;
#else
  // counts = iota(2n), halves of n; flat = concat(out0, out1); child j = (flat[2j], flat[2j+1])
  uint32_t w[2];
  for (int t = 0; t < 2; ++t) {
    uint32_t i = 2u * j + (uint32_t)t, a, b;
    if (i < n) { threefry2x32(k.hi, k.lo, i, i + n, a, b); w[t] = a; }
    else       { threefry2x32(k.hi, k.lo, i - n, i, a, b); w[t] = b; }
  }
  KeyPair r; r.hi = w[0]; r.lo = w[1]; return r;
#endif
}

__host__ __device__ __forceinline__ float bits_to_unit(uint32_t bits) {
  uint32_t fb = (bits >> 9) | 0x3F800000u;
  return __builtin_bit_cast(float, fb) - 1.0f;   // u in [0,1)
}

__device__ __forceinline__ float jax_uniform(KeyPair k, uint32_t i, uint32_t n, float mn, float mx) {
  float u = bits_to_unit(jax_rbits32(k, i, n));
  return fmaxf(mn, u * (mx - mn) + mn);
}

__global__ __launch_bounds__(256) void aug_kernel(const float* __restrict__ in,
                                                  float* __restrict__ out,
                                                  AugKeys K, int B) {
  const int b = blockIdx.x;
  const int tid = threadIdx.x;
  const uint32_t uB = (uint32_t)B;
  __shared__ float simg[3 * 64 * 64];   // 48 KB: one image
  __shared__ float red[4];

  // ---- per-batch params (each thread computes identical values; ~16 threefry + trig) ----
  const float DEG = 0.017453292519943295f;  // rounds to f32(pi/180)
  const float ang = jax_uniform(K.k1g, (uint32_t)b, uB, -25.f, 25.f) * DEG;
  const float shr = jax_uniform(K.k2g, (uint32_t)b, uB, -15.f, 15.f) * DEG;
  const float scl = jax_uniform(K.k3g, (uint32_t)b, uB, 0.85f, 1.15f);
  const float txp = jax_uniform(K.k4g, 2u * (uint32_t)b,      2u * uB, -0.15f, 0.15f) * 64.f;
  const float typ = jax_uniform(K.k4g, 2u * (uint32_t)b + 1u, 2u * uB, -0.15f, 0.15f) * 64.f;
  const float cA = cosf(ang), sA = sinf(ang), tS = tanf(shr);
  const float m00 = (cA - tS * (-sA)) / scl;
  const float m01 = (sA - tS * cA) / scl;
  const float m10 = (-sA) / scl;
  const float m11 = cA / scl;
  const bool  flip   = bits_to_unit(jax_rbits32(K.kf, (uint32_t)b, uB)) < 0.6f;
  const float bb     = jax_uniform(K.kbc, (uint32_t)b, uB, 0.7f, 1.3f);
  const float cc     = jax_uniform(K.kcc, (uint32_t)b, uB, 0.7f, 1.3f);
  const float ssat   = jax_uniform(K.ksc, (uint32_t)b, uB, 0.8f, 1.2f);
  const bool  doblur = bits_to_unit(jax_rbits32(K.kb, (uint32_t)b, uB)) < 0.3f;
  float area = jax_uniform(K.ka, (uint32_t)b, uB, 0.02f, 0.1f);
  area = area * 64.f;  // mirror reference's (u * H) * W evaluation order
  area = area * 64.f;
  const float ratio = jax_uniform(K.kr, (uint32_t)b, uB, 0.3f, 3.0f);
  const float eh = fminf(fmaxf(sqrtf(area * ratio), 1.f), 64.f);
  const float ew = fminf(fmaxf(sqrtf(area / ratio), 1.f), 64.f);
  const float topv  = bits_to_unit(jax_rbits32(K.kt, (uint32_t)b, uB)) * (64.f - eh);
  const float leftv = bits_to_unit(jax_rbits32(K.kl, (uint32_t)b, uB)) * (64.f - ew);
  const bool  apply_e = bits_to_unit(jax_rbits32(K.kp, (uint32_t)b, uB)) < 0.3f;
  const float dG = floorf(jax_uniform(K.kd, (uint32_t)b, uB, 8.f, 32.f));
  const float lG = floorf(dG * 0.6f);
  const bool  apply_g = bits_to_unit(jax_rbits32(K.kp2, (uint32_t)b, uB)) < 0.3f;
  const float t2 = topv + eh, l2 = leftv + ew;

  const float* __restrict__ inb = in + (size_t)b * 12288;

  // ---- phase 1: inverse-mapped affine warp + hflip into LDS; accumulate raw sum ----
  float lsum = 0.f;
  for (int p = tid; p < 12288; p += 256) {
    const int c = p >> 12;
    const int hw = p & 4095;
    const int h = hw >> 6;
    const int w = hw & 63;
    const int wsrc = flip ? (63 - w) : w;  // flip(warp(x))[w] == warp-output at 63-w
    const float gx = (float)wsrc - 31.5f;
    const float gy = (float)h - 31.5f;
    const float sx = (m00 * gx + m01 * gy) - txp + 31.5f;
    const float sy = (m10 * gx + m11 * gy) - typ + 31.5f;
    const float fx0 = floorf(sx), fy0 = floorf(sy);
    const float wx = sx - fx0, wy = sy - fy0;
    const int x0 = (int)fx0, y0 = (int)fy0;
    const float* pl = inb + c * 4096;
    auto tap = [&](int yy, int xx) -> float {
      const bool v = (xx >= 0) & (xx < 64) & (yy >= 0) & (yy < 64);
      const int yc = yy < 0 ? 0 : (yy > 63 ? 63 : yy);
      const int xc = xx < 0 ? 0 : (xx > 63 ? 63 : xx);
      return v ? pl[yc * 64 + xc] : 0.f;
    };
    float v = tap(y0, x0)         * (1.f - wx) * (1.f - wy)
            + tap(y0, x0 + 1)     * wx         * (1.f - wy)
            + tap(y0 + 1, x0)     * (1.f - wx) * wy
            + tap(y0 + 1, x0 + 1) * wx         * wy;
    simg[p] = v;
    lsum += v;
  }

  // ---- block reduction: mean of brightened image = bb * sum / N ----
  float wsum = lsum;
  for (int off = 32; off > 0; off >>= 1) wsum += __shfl_down(wsum, off);
  if ((tid & 63) == 0) red[tid >> 6] = wsum;
  __syncthreads();   // also covers phase-1 simg writes -> phase-2 reads
  const float mean = (bb * (red[0] + red[1] + red[2] + red[3])) / 12288.f;

  // ---- phase 2: brightness/contrast/saturation (per spatial position, in place) ----
  for (int q = tid; q < 4096; q += 256) {
    float r  = simg[q]        * bb;
    float g  = simg[4096 + q] * bb;
    float bl = simg[8192 + q] * bb;
    r  = (r  - mean) * cc + mean;
    g  = (g  - mean) * cc + mean;
    bl = (bl - mean) * cc + mean;
    const float gray = 0.299f * r + 0.587f * g + 0.114f * bl;
    r  = gray + (r  - gray) * ssat;
    g  = gray + (g  - gray) * ssat;
    bl = gray + (bl - gray) * ssat;
    simg[q] = r; simg[4096 + q] = g; simg[8192 + q] = bl;
  }
  __syncthreads();

  // ---- phase 3: 3x3 gaussian blur (zero-pad SAME) + erase + gridmask + clamp + store ----
  const uint32_t nfill = uB * 12288u;
  for (int p = tid; p < 12288; p += 256) {
    const int c = p >> 12;
    const int hw = p & 4095;
    const int h = hw >> 6;
    const int w = hw & 63;
    float v;
    if (doblur) {
      const float k1[3] = {0.25f, 0.5f, 0.25f};
      v = 0.f;
      for (int dy = -1; dy <= 1; ++dy) {
        const int hh = h + dy;
        if (hh < 0 || hh > 63) continue;
        for (int dx = -1; dx <= 1; ++dx) {
          const int ww = w + dx;
          if (ww < 0 || ww > 63) continue;
          v += simg[c * 4096 + hh * 64 + ww] * (k1[dy + 1] * k1[dx + 1]);
        }
      }
    } else {
      v = simg[p];
    }
    const float rowf = (float)h, colf = (float)w;
    if (apply_e && rowf >= topv && rowf < t2 && colf >= leftv && colf < l2) {
      const uint32_t idx = ((uint32_t)(b * 3 + c) << 12) | (uint32_t)(h << 6) | (uint32_t)w;
      v = bits_to_unit(jax_rbits32(K.kv, idx, nfill));  // uniform [0,1)
    }
    if (apply_g && (fmodf(rowf, dG) < lG) && (fmodf(colf, dG) < lG)) v = 0.f;
    v = fminf(fmaxf(v, 0.f), 1.f);
    out[(size_t)b * 12288 + p] = v;
  }
}

extern "C" void kernel_launch(void* const* d_in, const int* in_sizes, int n_in,
                              void* d_out, int out_size, void* d_ws, size_t ws_size,
                              hipStream_t stream) {
  (void)n_in; (void)out_size; (void)d_ws; (void)ws_size;
  const float* x = (const float*)d_in[0];
  float* out = (float*)d_out;
  const int B = in_sizes[0] / (3 * 64 * 64);
  if (B <= 0) return;

  // Host-side key derivation (pure arithmetic; graph-capture safe).
  KeyPair root; root.hi = 0u; root.lo = 42u;           // jax.random.key(42)
  KeyPair kg = jax_split_child(root, 0, 6);
  KeyPair kf = jax_split_child(root, 1, 6);
  KeyPair kc = jax_split_child(root, 2, 6);
  KeyPair kb = jax_split_child(root, 3, 6);
  KeyPair ke = jax_split_child(root, 4, 6);
  KeyPair km = jax_split_child(root, 5, 6);

  AugKeys K;
  K.k1g = jax_split_child(kg, 0, 4);
  K.k2g = jax_split_child(kg, 1, 4);
  K.k3g = jax_split_child(kg, 2, 4);
  K.k4g = jax_split_child(kg, 3, 4);
  K.kf  = kf;
  K.kbc = jax_split_child(kc, 0, 3);
  K.kcc = jax_split_child(kc, 1, 3);
  K.ksc = jax_split_child(kc, 2, 3);
  K.kb  = kb;
  K.ka  = jax_split_child(ke, 0, 6);
  K.kr  = jax_split_child(ke, 1, 6);
  K.kt  = jax_split_child(ke, 2, 6);
  K.kl  = jax_split_child(ke, 3, 6);
  K.kv  = jax_split_child(ke, 4, 6);
  K.kp  = jax_split_child(ke, 5, 6);
  K.kd  = jax_split_child(km, 0, 2);
  K.kp2 = jax_split_child(km, 1, 2);

  aug_kernel<<<dim3(B), dim3(256), 0, stream>>>(x, out, K, B);
}

// Round 2
// 237.893 us; speedup vs baseline: 1.3488x; 1.3488x over previous
//
#include <hip/hip_runtime.h>
#include <stdint.h>
#include <math.h>

// Match XLA's default (non-contracted) f32 arithmetic: keeps floor()/compare
// boundaries (bilinear taps, erase box, gridmask) aligned with the reference.
#pragma clang fp contract(off)

struct KeyPair { uint32_t hi, lo; };
struct KTab { KeyPair k[17]; };   // per-param derived keys, see host code

__host__ __device__ __forceinline__ uint32_t rotl32(uint32_t x, int r) {
  return (x << r) | (x >> (32 - r));
}

// JAX threefry2x32: 20 rounds, key injection every 4.
__host__ __device__ __forceinline__ void threefry2x32(uint32_t k0, uint32_t k1,
                                                      uint32_t x0, uint32_t x1,
                                                      uint32_t& o0, uint32_t& o1) {
  const uint32_t ks0 = k0, ks1 = k1, ks2 = k0 ^ k1 ^ 0x1BD11BDAu;
  x0 += ks0; x1 += ks1;
#define TF_R(r) { x0 += x1; x1 = rotl32(x1, (r)); x1 ^= x0; }
  TF_R(13) TF_R(15) TF_R(26) TF_R(6)
  x0 += ks1; x1 += ks2 + 1u;
  TF_R(17) TF_R(29) TF_R(16) TF_R(24)
  x0 += ks2; x1 += ks0 + 2u;
  TF_R(13) TF_R(15) TF_R(26) TF_R(6)
  x0 += ks0; x1 += ks1 + 3u;
  TF_R(17) TF_R(29) TF_R(16) TF_R(24)
  x0 += ks1; x1 += ks2 + 4u;
  TF_R(13) TF_R(15) TF_R(26) TF_R(6)
  x0 += ks2; x1 += ks0 + 5u;
#undef TF_R
  o0 = x0; o1 = x1;
}

// jax_threefry_partitionable=True 32-bit draw: fold both output words.
__host__ __device__ __forceinline__ uint32_t jax_rbits32(KeyPair k, uint32_t i) {
  uint32_t a, b; threefry2x32(k.hi, k.lo, 0u, i, a, b);
  return a ^ b;
}

__host__ __device__ __forceinline__ KeyPair jax_split_child(KeyPair k, uint32_t j) {
  uint32_t a, b; threefry2x32(k.hi, k.lo, 0u, j, a, b);
  KeyPair r; r.hi = a; r.lo = b; return r;
}

__host__ __device__ __forceinline__ float bits_to_unit(uint32_t bits) {
  uint32_t fb = (bits >> 9) | 0x3F800000u;
  return __builtin_bit_cast(float, fb) - 1.0f;   // u in [0,1)
}

__device__ __forceinline__ float map_u(float u, float mn, float mx) {
  return fmaxf(mn, u * (mx - mn) + mn);   // matches jax.random.uniform
}

struct SP {
  float m00, m01, m10, m11, txp, typ;
  float bb, cc, ssat;
  float topv, t2, leftv, l2;
  float dG, lG;
  int flip, doblur, apply_e, apply_g;
};

__global__ __launch_bounds__(512) void aug_kernel(const float* __restrict__ in,
                                                  float* __restrict__ out,
                                                  KTab KT, KeyPair kv, int B) {
  const int b = blockIdx.x;
  const int tid = threadIdx.x;
  __shared__ float simg[3 * 64 * 64];   // 48 KB: one image
  __shared__ float uarr[17];
  __shared__ SP sp;
  __shared__ unsigned long long mgrid, merow, mecol;
  __shared__ float red[8];

  // ---- phase 0a: lane-parallel raw uniform draws (one threefry chain, in parallel) ----
  if (tid < 17) {
    KeyPair k = KT.k[tid];
    uint32_t i = (tid == 3) ? 2u * (uint32_t)b
               : (tid == 4) ? 2u * (uint32_t)b + 1u
               : (uint32_t)b;
    uarr[tid] = bits_to_unit(jax_rbits32(k, i));
  }
  __syncthreads();

  // ---- phase 0b: lane 0 maps ranges, does trig, writes params ----
  if (tid == 0) {
    const float DEG = 0.017453292519943295f;
    float ang = map_u(uarr[0], -25.f, 25.f) * DEG;
    float shr = map_u(uarr[1], -15.f, 15.f) * DEG;
    float scl = map_u(uarr[2], 0.85f, 1.15f);
    sp.txp = map_u(uarr[3], -0.15f, 0.15f) * 64.f;
    sp.typ = map_u(uarr[4], -0.15f, 0.15f) * 64.f;
    float cA = cosf(ang), sA = sinf(ang), tS = tanf(shr);
    sp.m00 = (cA - tS * (-sA)) / scl;
    sp.m01 = (sA - tS * cA) / scl;
    sp.m10 = (-sA) / scl;
    sp.m11 = cA / scl;
    sp.flip = uarr[5] < 0.6f;
    sp.bb = map_u(uarr[6], 0.7f, 1.3f);
    sp.cc = map_u(uarr[7], 0.7f, 1.3f);
    sp.ssat = map_u(uarr[8], 0.8f, 1.2f);
    sp.doblur = uarr[9] < 0.3f;
    float area = map_u(uarr[10], 0.02f, 0.1f);
    area = area * 64.f;   // mirror reference's (u * H) * W evaluation order
    area = area * 64.f;
    float ratio = map_u(uarr[11], 0.3f, 3.0f);
    float eh = fminf(fmaxf(sqrtf(area * ratio), 1.f), 64.f);
    float ew = fminf(fmaxf(sqrtf(area / ratio), 1.f), 64.f);
    float topv = uarr[12] * (64.f - eh);
    float leftv = uarr[13] * (64.f - ew);
    sp.topv = topv; sp.t2 = topv + eh;
    sp.leftv = leftv; sp.l2 = leftv + ew;
    sp.apply_e = uarr[14] < 0.3f;
    float dG = floorf(map_u(uarr[15], 8.f, 32.f));
    sp.dG = dG;
    sp.lG = floorf(dG * 0.6f);
    sp.apply_g = uarr[16] < 0.3f;
  }
  __syncthreads();

  // ---- phase 0c: 64-bit row/col masks via ballot (H == W == 64) ----
  if (tid < 64) {
    float rf = (float)tid;
    unsigned long long g = __ballot(fmodf(rf, sp.dG) < sp.lG);       // grid rows==cols
    unsigned long long er = __ballot((rf >= sp.topv) & (rf < sp.t2));
    unsigned long long ec = __ballot((rf >= sp.leftv) & (rf < sp.l2));
    if (tid == 0) { mgrid = g; merow = er; mecol = ec; }
  }
  __syncthreads();

  // snapshot params into registers
  const float m00 = sp.m00, m01 = sp.m01, m10 = sp.m10, m11 = sp.m11;
  const float txp = sp.txp, typ = sp.typ;
  const float bb = sp.bb, cc = sp.cc, ssat = sp.ssat;
  const int flip = sp.flip, doblur = sp.doblur;
  const int apply_e = sp.apply_e, apply_g = sp.apply_g;
  const unsigned long long mg = mgrid, mer = merow, mec = mecol;

  const float* __restrict__ inb = in + (size_t)b * 12288;

  // ---- phase 1: affine warp + hflip into LDS (float4 quads); accumulate raw sum ----
  float lsum = 0.f;
#pragma unroll 1
  for (int it = 0; it < 6; ++it) {
    const int p = 4 * tid + it * 2048;
    const int c = p >> 12;
    const int hw = p & 4095;
    const int h = hw >> 6;
    const int w0 = hw & 63;
    const float* pl = inb + c * 4096;
    const float gy = (float)h - 31.5f;
    float vv[4];
#pragma unroll
    for (int j = 0; j < 4; ++j) {
      const int w = w0 + j;
      const int wsrc = flip ? (63 - w) : w;   // flip(warp(x))[w] == warp-out at 63-w
      const float gx = (float)wsrc - 31.5f;
      const float sx = (m00 * gx + m01 * gy) - txp + 31.5f;
      const float sy = (m10 * gx + m11 * gy) - typ + 31.5f;
      const float fx0 = floorf(sx), fy0 = floorf(sy);
      const float wx = sx - fx0, wy = sy - fy0;
      const int x0 = (int)fx0, y0 = (int)fy0;
      auto tap = [&](int yy, int xx) -> float {
        const bool v = (xx >= 0) & (xx < 64) & (yy >= 0) & (yy < 64);
        const int yc = yy < 0 ? 0 : (yy > 63 ? 63 : yy);
        const int xc = xx < 0 ? 0 : (xx > 63 ? 63 : xx);
        return v ? pl[yc * 64 + xc] : 0.f;
      };
      float v = tap(y0, x0)         * (1.f - wx) * (1.f - wy)
              + tap(y0, x0 + 1)     * wx         * (1.f - wy)
              + tap(y0 + 1, x0)     * (1.f - wx) * wy
              + tap(y0 + 1, x0 + 1) * wx         * wy;
      vv[j] = v;
      lsum += v;
    }
    float4 st; st.x = vv[0]; st.y = vv[1]; st.z = vv[2]; st.w = vv[3];
    *(float4*)&simg[p] = st;
  }

  // ---- block reduction over 8 waves: mean of brightened image = bb * sum / N ----
  float wsum = lsum;
  for (int off = 32; off > 0; off >>= 1) wsum += __shfl_down(wsum, off);
  if ((tid & 63) == 0) red[tid >> 6] = wsum;
  __syncthreads();   // also covers phase-1 simg writes -> phase-2 reads
  const float mean = (bb * (red[0] + red[1] + red[2] + red[3] +
                            red[4] + red[5] + red[6] + red[7])) / 12288.f;

  // ---- phase 2: brightness/contrast/saturation, float4 per plane, in place ----
#pragma unroll 1
  for (int it = 0; it < 2; ++it) {
    const int q = 4 * tid + it * 2048;
    float4 r4 = *(const float4*)&simg[q];
    float4 g4 = *(const float4*)&simg[4096 + q];
    float4 b4 = *(const float4*)&simg[8192 + q];
    float rr[4] = {r4.x, r4.y, r4.z, r4.w};
    float gg[4] = {g4.x, g4.y, g4.z, g4.w};
    float bl[4] = {b4.x, b4.y, b4.z, b4.w};
#pragma unroll
    for (int j = 0; j < 4; ++j) {
      float r = rr[j] * bb, g = gg[j] * bb, bz = bl[j] * bb;
      r = (r - mean) * cc + mean;
      g = (g - mean) * cc + mean;
      bz = (bz - mean) * cc + mean;
      const float gray = 0.299f * r + 0.587f * g + 0.114f * bz;
      rr[j] = gray + (r - gray) * ssat;
      gg[j] = gray + (g - gray) * ssat;
      bl[j] = gray + (bz - gray) * ssat;
    }
    r4.x = rr[0]; r4.y = rr[1]; r4.z = rr[2]; r4.w = rr[3];
    g4.x = gg[0]; g4.y = gg[1]; g4.z = gg[2]; g4.w = gg[3];
    b4.x = bl[0]; b4.y = bl[1]; b4.z = bl[2]; b4.w = bl[3];
    *(float4*)&simg[q] = r4;
    *(float4*)&simg[4096 + q] = g4;
    *(float4*)&simg[8192 + q] = b4;
  }
  __syncthreads();

  // ---- phase 3: separable 3x3 blur + erase + gridmask + clamp + float4 store ----
#pragma unroll 1
  for (int it = 0; it < 6; ++it) {
    const int p = 4 * tid + it * 2048;
    const int c = p >> 12;
    const int hw = p & 4095;
    const int h = hw >> 6;
    const int w0 = hw & 63;
    float o[4];
    if (doblur) {
      float win[3][6];
#pragma unroll
      for (int r = 0; r < 3; ++r) {
        const int hh = h - 1 + r;
        if (hh >= 0 && hh <= 63) {
          const float* row = &simg[c * 4096 + hh * 64];
          const float4 c4 = *(const float4*)&row[w0];
          win[r][1] = c4.x; win[r][2] = c4.y; win[r][3] = c4.z; win[r][4] = c4.w;
          win[r][0] = (w0 > 0)  ? row[w0 - 1] : 0.f;
          win[r][5] = (w0 < 60) ? row[w0 + 4] : 0.f;
        } else {
          win[r][0] = win[r][1] = win[r][2] = win[r][3] = win[r][4] = win[r][5] = 0.f;
        }
      }
#pragma unroll
      for (int j = 0; j < 4; ++j) {
        const float h0 = 0.25f * win[0][j] + 0.5f * win[0][j + 1] + 0.25f * win[0][j + 2];
        const float h1 = 0.25f * win[1][j] + 0.5f * win[1][j + 1] + 0.25f * win[1][j + 2];
        const float h2 = 0.25f * win[2][j] + 0.5f * win[2][j + 1] + 0.25f * win[2][j + 2];
        o[j] = 0.25f * h0 + 0.5f * h1 + 0.25f * h2;
      }
    } else {
      const float4 c4 = *(const float4*)&simg[p];
      o[0] = c4.x; o[1] = c4.y; o[2] = c4.z; o[3] = c4.w;
    }
    const bool erow_b = apply_e && ((mer >> h) & 1ull);
    const bool grow_b = apply_g && ((mg >> h) & 1ull);
#pragma unroll
    for (int j = 0; j < 4; ++j) {
      const int w = w0 + j;
      if (erow_b && ((mec >> w) & 1ull)) {
        const uint32_t idx = ((uint32_t)(b * 3 + c) << 12) | (uint32_t)(h << 6) | (uint32_t)w;
        o[j] = bits_to_unit(jax_rbits32(kv, idx));   // uniform fill [0,1)
      }
      if (grow_b && ((mg >> w) & 1ull)) o[j] = 0.f;
      o[j] = fminf(fmaxf(o[j], 0.f), 1.f);
    }
    float4 st; st.x = o[0]; st.y = o[1]; st.z = o[2]; st.w = o[3];
    *(float4*)&out[(size_t)b * 12288 + p] = st;
  }
}

extern "C" void kernel_launch(void* const* d_in, const int* in_sizes, int n_in,
                              void* d_out, int out_size, void* d_ws, size_t ws_size,
                              hipStream_t stream) {
  (void)n_in; (void)out_size; (void)d_ws; (void)ws_size;
  const float* x = (const float*)d_in[0];
  float* out = (float*)d_out;
  const int B = in_sizes[0] / (3 * 64 * 64);
  if (B <= 0) return;

  // Host-side key derivation (pure arithmetic; graph-capture safe).
  KeyPair root; root.hi = 0u; root.lo = 42u;           // jax.random.key(42)
  KeyPair kg = jax_split_child(root, 0);
  KeyPair kf = jax_split_child(root, 1);
  KeyPair kc = jax_split_child(root, 2);
  KeyPair kb = jax_split_child(root, 3);
  KeyPair ke = jax_split_child(root, 4);
  KeyPair km = jax_split_child(root, 5);

  KTab KT;
  KT.k[0]  = jax_split_child(kg, 0);   // angle
  KT.k[1]  = jax_split_child(kg, 1);   // shear
  KT.k[2]  = jax_split_child(kg, 2);   // scale
  KT.k[3]  = jax_split_child(kg, 3);   // translate x (idx 2b)
  KT.k[4]  = KT.k[3];                  // translate y (idx 2b+1)
  KT.k[5]  = kf;                       // hflip
  KT.k[6]  = jax_split_child(kc, 0);   // brightness
  KT.k[7]  = jax_split_child(kc, 1);   // contrast
  KT.k[8]  = jax_split_child(kc, 2);   // saturation
  KT.k[9]  = kb;                       // blur
  KT.k[10] = jax_split_child(ke, 0);   // area
  KT.k[11] = jax_split_child(ke, 1);   // ratio
  KT.k[12] = jax_split_child(ke, 2);   // top
  KT.k[13] = jax_split_child(ke, 3);   // left
  KT.k[14] = jax_split_child(ke, 5);   // apply (erase)
  KT.k[15] = jax_split_child(km, 0);   // grid d
  KT.k[16] = jax_split_child(km, 1);   // apply (grid)
  KeyPair kv = jax_split_child(ke, 4); // erase fill values

  aug_kernel<<<dim3(B), dim3(512), 0, stream>>>(x, out, KT, kv, B);
}